// Round 1
// baseline (17340.546 us; speedup 1.0000x reference)
//
#include <hip/hip_runtime.h>
#include <hip/hip_bf16.h>

#define B 512
#define S 64
#define H 1024
#define O 1024
#define T 128
#define ATT 64

typedef __bf16 bf16;
typedef __bf16 bf16x8 __attribute__((ext_vector_type(8)));
typedef __bf16 bf16x4 __attribute__((ext_vector_type(4)));
typedef float f32x4 __attribute__((ext_vector_type(4)));

static __device__ __forceinline__ float bf2f(bf16 b) {
    unsigned short s = __builtin_bit_cast(unsigned short, b);
    unsigned int u = ((unsigned int)s) << 16;
    return __builtin_bit_cast(float, u);
}
static __device__ __forceinline__ bf16 f2bf(float f) {
    unsigned int u = __builtin_bit_cast(unsigned int, f);
    unsigned int r = (u + 0x7fffu + ((u >> 16) & 1u)) >> 16;
    return __builtin_bit_cast(bf16, (unsigned short)r);
}

// ---------------------------------------------------------------------------
// Generic bf16 MFMA GEMM:  C[M,N] = act(A @ W^T + bias)
// A is split into two K-segments (physical concat avoidance):
//   k <  splitK : A0 [M, splitK]
//   k >= splitK : A1 [M, K-splitK]
// W is [N, K] row-major (so both operands are K-contiguous).
// Block: 256 thr = 4 waves in 2x2; block tile 32(M) x 64(N); wave tile 16x32.
// grid = (N/64, M/32)
// ---------------------------------------------------------------------------
template <bool RELU>
__global__ __launch_bounds__(256) void gemm_kernel(
    const bf16* __restrict__ A0, const bf16* __restrict__ A1, int splitK,
    const bf16* __restrict__ W, const float* __restrict__ bias, int K,
    float* __restrict__ Cf, long ldc, bf16* __restrict__ Cbf, int ldcbf) {
    const int tid = threadIdx.x;
    const int wave = tid >> 6, lane = tid & 63;
    const int wm = wave >> 1, wn = wave & 1;
    const int quad = lane >> 4, r = lane & 15;
    const int kq = quad * 8;

    const int m0 = blockIdx.y * 32 + wm * 16 + r;   // A row this lane loads
    const int n0 = blockIdx.x * 64 + wn * 32;       // wave's base output col

    const int lda0 = splitK, lda1 = K - splitK;
    const bf16* a0row = A0 + (long)m0 * lda0;
    const bf16* a1row = A1 + (long)m0 * lda1;
    const bf16* w0 = W + (long)(n0 + r) * K;        // ni=0 weight row
    const bf16* w1 = W + (long)(n0 + 16 + r) * K;   // ni=1 weight row

    f32x4 acc0 = {0.f, 0.f, 0.f, 0.f}, acc1 = {0.f, 0.f, 0.f, 0.f};

    for (int k0 = 0; k0 < K; k0 += 32) {
        bf16x8 av;
        if (k0 < splitK)
            av = *(const bf16x8*)(a0row + k0 + kq);
        else
            av = *(const bf16x8*)(a1row + (k0 - splitK) + kq);
        bf16x8 bv0 = *(const bf16x8*)(w0 + k0 + kq);
        bf16x8 bv1 = *(const bf16x8*)(w1 + k0 + kq);
        acc0 = __builtin_amdgcn_mfma_f32_16x16x32_bf16(av, bv0, acc0, 0, 0, 0);
        acc1 = __builtin_amdgcn_mfma_f32_16x16x32_bf16(av, bv1, acc1, 0, 0, 0);
    }

    // D layout: col = lane&15, row = quad*4 + reg  (m89/m91-verified)
    const int mbase = blockIdx.y * 32 + wm * 16 + quad * 4;
    const int nA = n0 + r, nB = n0 + 16 + r;
    const float biasA = bias[nA], biasB = bias[nB];
#pragma unroll
    for (int reg = 0; reg < 4; ++reg) {
        const int m = mbase + reg;
        float vA = acc0[reg] + biasA;
        float vB = acc1[reg] + biasB;
        if (RELU) { vA = fmaxf(vA, 0.f); vB = fmaxf(vB, 0.f); }
        if (Cf) {
            Cf[(long)m * ldc + nA] = vA;
            Cf[(long)m * ldc + nB] = vB;
        }
        if (Cbf) {
            Cbf[(long)m * ldcbf + nA] = f2bf(vA);
            Cbf[(long)m * ldcbf + nB] = f2bf(vB);
        }
    }
}

// ---------------------------------------------------------------------------
// Attention logits + softmax: logits = [dec | h] @ Wa^T + ba  -> softmax rows
// N = 64 (whole logit row in one block), M tile 32. grid = (1, B/32)
// ---------------------------------------------------------------------------
__global__ __launch_bounds__(256) void attn_logits_kernel(
    const bf16* __restrict__ dec, const bf16* __restrict__ h,
    const bf16* __restrict__ Wa, const float* __restrict__ ba,
    bf16* __restrict__ attn_w) {
    __shared__ float lg[32][64];
    const int tid = threadIdx.x;
    const int wave = tid >> 6, lane = tid & 63;
    const int wm = wave >> 1, wn = wave & 1;
    const int quad = lane >> 4, r = lane & 15;
    const int kq = quad * 8;

    const int m0 = blockIdx.y * 32 + wm * 16 + r;
    const int n0 = wn * 32;

    const bf16* drow = dec + (long)m0 * H;
    const bf16* hrow = h + (long)m0 * H;
    const bf16* w0 = Wa + (long)(n0 + r) * 2048;
    const bf16* w1 = Wa + (long)(n0 + 16 + r) * 2048;

    f32x4 acc0 = {0.f, 0.f, 0.f, 0.f}, acc1 = {0.f, 0.f, 0.f, 0.f};
    for (int k0 = 0; k0 < 2048; k0 += 32) {
        bf16x8 av;
        if (k0 < 1024)
            av = *(const bf16x8*)(drow + k0 + kq);
        else
            av = *(const bf16x8*)(hrow + (k0 - 1024) + kq);
        bf16x8 bv0 = *(const bf16x8*)(w0 + k0 + kq);
        bf16x8 bv1 = *(const bf16x8*)(w1 + k0 + kq);
        acc0 = __builtin_amdgcn_mfma_f32_16x16x32_bf16(av, bv0, acc0, 0, 0, 0);
        acc1 = __builtin_amdgcn_mfma_f32_16x16x32_bf16(av, bv1, acc1, 0, 0, 0);
    }

    const int mloc = wm * 16 + quad * 4;
#pragma unroll
    for (int reg = 0; reg < 4; ++reg) {
        lg[mloc + reg][n0 + r] = acc0[reg] + ba[n0 + r];
        lg[mloc + reg][n0 + 16 + r] = acc1[reg] + ba[n0 + 16 + r];
    }
    __syncthreads();

    if (tid < 32) {
        const int row = tid;
        float mx = -1e30f;
#pragma unroll
        for (int s = 0; s < 64; ++s) mx = fmaxf(mx, lg[row][s]);
        float sum = 0.f;
#pragma unroll
        for (int s = 0; s < 64; ++s) sum += __expf(lg[row][s] - mx);
        const float inv = 1.f / sum;
        const long gb = (long)(blockIdx.y * 32 + row) * 64;
#pragma unroll
        for (int s = 0; s < 64; ++s)
            attn_w[gb + s] = f2bf(__expf(lg[row][s] - mx) * inv);
    }
}

// ---------------------------------------------------------------------------
// attn_applied[b,d] = sum_s w[b,s] * enc[b,s,d].  grid = B*4, block 256.
// ---------------------------------------------------------------------------
__global__ __launch_bounds__(256) void attn_apply_kernel(
    const bf16* __restrict__ attn_w, const bf16* __restrict__ enc,
    bf16* __restrict__ attn_out) {
    __shared__ float w[64];
    const int b = blockIdx.x >> 2;
    const int d = ((blockIdx.x & 3) << 8) + threadIdx.x;
    if (threadIdx.x < 64) w[threadIdx.x] = bf2f(attn_w[b * 64 + threadIdx.x]);
    __syncthreads();
    const bf16* e = enc + (long)b * (S * 1024) + d;
    float acc = 0.f;
#pragma unroll 8
    for (int s = 0; s < S; ++s) acc += w[s] * bf2f(e[(long)s * 1024]);
    attn_out[(long)b * 1024 + d] = f2bf(acc);
}

// ---------------------------------------------------------------------------
// Fused GRU: 6 simultaneous GEMM accumulations (gi_{r,z,n}, gh_{r,z,n})
// + gate math + h_new writeback (fp32 + bf16). grid = (H/64, B/32).
// ---------------------------------------------------------------------------
__global__ __launch_bounds__(256) void gru_kernel(
    const bf16* __restrict__ gin, const bf16* __restrict__ hbf,
    const bf16* __restrict__ Wih, const bf16* __restrict__ Whh,
    const float* __restrict__ bih, const float* __restrict__ bhh,
    const float* __restrict__ hold, float* __restrict__ hnew,
    bf16* __restrict__ hnewbf) {
    const int tid = threadIdx.x;
    const int wave = tid >> 6, lane = tid & 63;
    const int wm = wave >> 1, wn = wave & 1;
    const int quad = lane >> 4, r = lane & 15;
    const int kq = quad * 8;

    const int m0 = blockIdx.y * 32 + wm * 16 + r;
    const int n0 = blockIdx.x * 64 + wn * 32;

    const bf16* grow = gin + (long)m0 * H;
    const bf16* hrow = hbf + (long)m0 * H;

    // weight row pointers: gate g uses rows [g*H + j]
    const bf16* wi[3][2];
    const bf16* wh[3][2];
#pragma unroll
    for (int g = 0; g < 3; ++g) {
#pragma unroll
        for (int ni = 0; ni < 2; ++ni) {
            const long row = (long)g * H + n0 + ni * 16 + r;
            wi[g][ni] = Wih + row * H;
            wh[g][ni] = Whh + row * H;
        }
    }

    f32x4 aI[3][2], aH[3][2];
#pragma unroll
    for (int g = 0; g < 3; ++g)
#pragma unroll
        for (int ni = 0; ni < 2; ++ni) {
            aI[g][ni] = (f32x4){0.f, 0.f, 0.f, 0.f};
            aH[g][ni] = (f32x4){0.f, 0.f, 0.f, 0.f};
        }

    for (int k0 = 0; k0 < H; k0 += 32) {
        const int ko = k0 + kq;
        bf16x8 ai = *(const bf16x8*)(grow + ko);
        bf16x8 ah = *(const bf16x8*)(hrow + ko);
#pragma unroll
        for (int g = 0; g < 3; ++g) {
#pragma unroll
            for (int ni = 0; ni < 2; ++ni) {
                bf16x8 bi = *(const bf16x8*)(wi[g][ni] + ko);
                aI[g][ni] = __builtin_amdgcn_mfma_f32_16x16x32_bf16(ai, bi, aI[g][ni], 0, 0, 0);
                bf16x8 bh = *(const bf16x8*)(wh[g][ni] + ko);
                aH[g][ni] = __builtin_amdgcn_mfma_f32_16x16x32_bf16(ah, bh, aH[g][ni], 0, 0, 0);
            }
        }
    }

    const int mbase = blockIdx.y * 32 + wm * 16 + quad * 4;
#pragma unroll
    for (int ni = 0; ni < 2; ++ni) {
        const int j = n0 + ni * 16 + r;
        const float bir = bih[j], biz = bih[j + H], bin = bih[j + 2 * H];
        const float bhr = bhh[j], bhz = bhh[j + H], bhn = bhh[j + 2 * H];
#pragma unroll
        for (int reg = 0; reg < 4; ++reg) {
            const int m = mbase + reg;
            const float gir = aI[0][ni][reg] + bir, ghr = aH[0][ni][reg] + bhr;
            const float giz = aI[1][ni][reg] + biz, ghz = aH[1][ni][reg] + bhz;
            const float ginv = aI[2][ni][reg] + bin, ghn = aH[2][ni][reg] + bhn;
            const float rg = 1.f / (1.f + __expf(-(gir + ghr)));
            const float zg = 1.f / (1.f + __expf(-(giz + ghz)));
            const float ng = tanhf(ginv + rg * ghn);
            const long idx = (long)m * H + j;
            const float hv = hold[idx];
            const float hnv = (1.f - zg) * ng + zg * hv;
            hnew[idx] = hnv;
            hnewbf[idx] = f2bf(hnv);
        }
    }
}

// ---------------------------------------------------------------------------
// init / utility kernels
// ---------------------------------------------------------------------------
__global__ __launch_bounds__(256) void cast_kernel(
    const float* __restrict__ src, bf16* __restrict__ dst, long n4) {
    long i = (long)blockIdx.x * blockDim.x + threadIdx.x;
    const long stride = (long)gridDim.x * blockDim.x;
    for (; i < n4; i += stride) {
        float4 v = ((const float4*)src)[i];
        bf16x4 o = {f2bf(v.x), f2bf(v.y), f2bf(v.z), f2bf(v.w)};
        *(bf16x4*)(dst + 4 * i) = o;
    }
}

__global__ __launch_bounds__(256) void init_h_kernel(
    const float* __restrict__ h0, float* __restrict__ hfp,
    bf16* __restrict__ hbf, long n4) {
    long i = (long)blockIdx.x * blockDim.x + threadIdx.x;
    const long stride = (long)gridDim.x * blockDim.x;
    for (; i < n4; i += stride) {
        float4 v = ((const float4*)h0)[i];
        ((float4*)hfp)[i] = v;
        bf16x4 o = {f2bf(v.x), f2bf(v.y), f2bf(v.z), f2bf(v.w)};
        *(bf16x4*)(hbf + 4 * i) = o;
    }
}

__global__ __launch_bounds__(256) void copy_f32_kernel(
    const float* __restrict__ src, float* __restrict__ dst, long n4) {
    long i = (long)blockIdx.x * blockDim.x + threadIdx.x;
    const long stride = (long)gridDim.x * blockDim.x;
    for (; i < n4; i += stride) ((float4*)dst)[i] = ((const float4*)src)[i];
}

// ---------------------------------------------------------------------------
extern "C" void kernel_launch(void* const* d_in, const int* in_sizes, int n_in,
                              void* d_out, int out_size, void* d_ws, size_t ws_size,
                              hipStream_t stream) {
    const float* enc_f = (const float*)d_in[0];
    const float* hidden = (const float*)d_in[1];
    // d_in[2] = max_length (always 128 for this problem)
    const float* Wa = (const float*)d_in[3];
    const float* ba = (const float*)d_in[4];
    const float* Wc = (const float*)d_in[5];
    const float* bc = (const float*)d_in[6];
    const float* Wih = (const float*)d_in[7];
    const float* Whh = (const float*)d_in[8];
    const float* bih = (const float*)d_in[9];
    const float* bhh = (const float*)d_in[10];
    const float* Wo = (const float*)d_in[11];
    const float* bo = (const float*)d_in[12];
    float* out = (float*)d_out;

    // ---- workspace carve-up (bf16 buffers then fp32 buffers) ----
    char* p = (char*)d_ws;
    auto carve = [&](long bytes) {
        char* q = p;
        p += (bytes + 255) & ~255L;
        return q;
    };
    bf16* Wa_bf  = (bf16*)carve((long)ATT * 2048 * 2);
    bf16* Wc_bf  = (bf16*)carve((long)H * 2048 * 2);
    bf16* Wih_bf = (bf16*)carve((long)3 * H * H * 2);
    bf16* Whh_bf = (bf16*)carve((long)3 * H * H * 2);
    bf16* Wo_bf  = (bf16*)carve((long)O * H * 2);
    bf16* enc_bf = (bf16*)carve((long)B * S * 1024 * 2);
    bf16* dec_bf = (bf16*)carve((long)B * O * 2);
    bf16* attn_bf = (bf16*)carve((long)B * 1024 * 2);
    bf16* gru_bf = (bf16*)carve((long)B * H * 2);
    bf16* hbfA = (bf16*)carve((long)B * H * 2);
    bf16* hbfB = (bf16*)carve((long)B * H * 2);
    bf16* attn_w = (bf16*)carve((long)B * 64 * 2);
    float* hfpA = (float*)carve((long)B * H * 4);
    float* hfpB = (float*)carve((long)B * H * 4);

    // ---- init: zeros for dec_in(t=0), bf16 casts of weights/enc, h0 ----
    hipMemsetAsync(dec_bf, 0, (long)B * O * 2, stream);
    auto cast = [&](const float* s, bf16* d, long n) {
        long n4 = n / 4;
        int blocks = (int)((n4 + 255) / 256);
        if (blocks > 4096) blocks = 4096;
        cast_kernel<<<blocks, 256, 0, stream>>>(s, d, n4);
    };
    cast(Wa, Wa_bf, (long)ATT * 2048);
    cast(Wc, Wc_bf, (long)H * 2048);
    cast(Wih, Wih_bf, (long)3 * H * H);
    cast(Whh, Whh_bf, (long)3 * H * H);
    cast(Wo, Wo_bf, (long)O * H);
    cast(enc_f, enc_bf, (long)B * S * 1024);
    init_h_kernel<<<512, 256, 0, stream>>>(hidden, hfpA, hbfA, (long)B * H / 4);

    const dim3 blk(256);
    const dim3 grid_gemm(H / 64, B / 32);     // (16,16)
    const dim3 grid_attn(1, B / 32);          // (1,16)

    for (int t = 0; t < T; ++t) {
        const bf16* hbf_r = (t & 1) ? hbfB : hbfA;
        bf16* hbf_w = (t & 1) ? hbfA : hbfB;
        const float* hfp_r = (t & 1) ? hfpB : hfpA;
        float* hfp_w = (t & 1) ? hfpA : hfpB;

        // 1) attention logits + softmax
        attn_logits_kernel<<<grid_attn, blk, 0, stream>>>(dec_bf, hbf_r, Wa_bf, ba, attn_w);
        // 2) attention apply
        attn_apply_kernel<<<B * 4, blk, 0, stream>>>(attn_w, enc_bf, attn_bf);
        // 3) combine + relu -> gru_in (bf16)
        gemm_kernel<true><<<grid_gemm, blk, 0, stream>>>(
            dec_bf, attn_bf, 1024, Wc_bf, bc, 2048, nullptr, 0, gru_bf, H);
        // 4) fused GRU -> h_new (fp32 + bf16)
        gru_kernel<<<grid_gemm, blk, 0, stream>>>(
            gru_bf, hbf_r, Wih_bf, Whh_bf, bih, bhh, hfp_r, hfp_w, hbf_w);
        // 5) fc_out -> d_out[:, t, :] (fp32) and dec_bf (bf16) for next step
        gemm_kernel<false><<<grid_gemm, blk, 0, stream>>>(
            hbf_w, hbf_w, 1024, Wo_bf, bo, 1024,
            out + (long)t * O, (long)T * O, dec_bf, O);
    }

    // final hidden -> tail of d_out (after 128 steps final h is in hfpA)
    copy_f32_kernel<<<512, 256, 0, stream>>>(hfpA, out + (long)B * T * O, (long)B * H / 4);
}